// Round 8
// baseline (351.645 us; speedup 1.0000x reference)
//
#include <hip/hip_runtime.h>
#include <hip/hip_bf16.h>

#define NN 16000
#define EE 256000
#define CC 64
#define AA 10
#define RR 8
#define NC9 9216000      // N*C*9
#define SC_OFF 18432000  // 2*N*C*9

// ---------------- workspace layout (bytes) ----------------
#define WS_H        0
#define WS_BLK      4096000     // [E][28] f32, CSR-slot order
#define WS_WLT      32768256    // [3][64][64] f32 (W_lin transposed)
#define WS_SPECIES  32817408
#define WS_COUNTS   32881408
#define WS_CURSOR   32945408
#define WS_OFFSETS  33009408    // [N+1]
#define WS_PERM     33073472    // [N] degree-sorted node ids
#define WS_DSTART   33137472    // [64]
#define WS_DEGCUR   33137728    // [64]

__device__ __forceinline__ float comp4(float4 v, int j) {
  return j == 0 ? v.x : j == 1 ? v.y : j == 2 ? v.z : v.w;
}

// species + edge histogram + W_lin transpose + h/sc node matmuls
__global__ __launch_bounds__(256) void prep_kernel(
    const float* __restrict__ attrs, const int* __restrict__ recv,
    const float* __restrict__ W_lin, const float* __restrict__ nf,
    const float* __restrict__ W_up, const float* __restrict__ W_skip,
    int* __restrict__ species, int* __restrict__ counts,
    float* __restrict__ wlt, float* __restrict__ h, float* __restrict__ out) {
  __shared__ float sW[4096];
  for (int t = threadIdx.x; t < 4096; t += 256) sW[t] = W_up[t];
  __syncthreads();
  int i = blockIdx.x * 256 + threadIdx.x;
  if (i < NN) {
    const float* p = attrs + (size_t)i * AA;
    int sp = 0;
#pragma unroll
    for (int a = 1; a < AA; ++a)
      if (p[a] > 0.5f) sp = a;
    species[i] = sp;
  }
  if (i < 3 * 64 * 64) {  // wlt[l][v][u] = W_lin[l][u][v]
    int l = i >> 12, rem = i & 4095, v = rem >> 6, u = rem & 63;
    wlt[i] = W_lin[l * 4096 + u * 64 + v];
  }
  if (i < EE) atomicAdd(&counts[recv[i]], 1);
  // h = (nf @ W_up)/8 ; sc = (nf . W_skip[:,a,:])/sqrt(640)
  int wid = __builtin_amdgcn_readfirstlane(threadIdx.x >> 6);
  int lane = threadIdx.x & 63;
  for (int n = blockIdx.x * 4 + wid; n < NN; n += 4000) {
    const float* ap = attrs + (size_t)n * AA;  // uniform -> s_load
    int a = 0;
#pragma unroll
    for (int j = 1; j < AA; ++j)
      if (ap[j] > 0.5f) a = j;
    const float* nfp = nf + (size_t)n * 64;
    const float* wsk = W_skip + (size_t)a * 64;
    float hacc = 0.f, sacc = 0.f;
#pragma unroll
    for (int u = 0; u < 64; ++u) {
      float x = nfp[u];  // uniform -> s_load
      hacc = fmaf(x, sW[u * 64 + lane], hacc);
      sacc = fmaf(x, wsk[u * 640 + lane], sacc);
    }
    h[(size_t)n * 64 + lane] = hacc * 0.125f;
    out[SC_OFF + (size_t)n * 64 + lane] = sacc * 0.03952847075210474f;
  }
}

// single block: exclusive scan counts->offsets, plus descending degree-bucket
// starts for the balance sort
__global__ __launch_bounds__(1024) void scan_kernel(
    const int* __restrict__ counts, int* __restrict__ offsets,
    int* __restrict__ dstart, int* __restrict__ degcur) {
  __shared__ int part[1024];
  __shared__ int hist[64];
  int tid = threadIdx.x;
  if (tid < 64) { hist[tid] = 0; degcur[tid] = 0; }
  const int CH = 16;
  int base = tid * CH;
  int loc[CH];
  int s = 0;
#pragma unroll
  for (int i = 0; i < CH; ++i) {
    int idx = base + i;
    int c = (idx < NN) ? counts[idx] : 0;
    loc[i] = c;
    s += c;
  }
  part[tid] = s;
  __syncthreads();
  for (int off = 1; off < 1024; off <<= 1) {
    int t = part[tid];
    int add = (tid >= off) ? part[tid - off] : 0;
    __syncthreads();
    part[tid] = t + add;
    __syncthreads();
  }
  int pre = (tid > 0) ? part[tid - 1] : 0;
#pragma unroll
  for (int i = 0; i < CH; ++i) {
    int idx = base + i;
    if (idx <= NN) offsets[idx] = pre;
    pre += loc[i];
    if (idx < NN) atomicAdd(&hist[min(loc[i], 63)], 1);
  }
  __syncthreads();
  if (tid == 0) {
    int run = 0;
    for (int d = 63; d >= 0; --d) { dstart[d] = run; run += hist[d]; }
  }
}

// CSR scatter: packed 112-B per-SLOT edge block + degree-sorted node perm
// dw0 = s|(a<<20); dw1-8 = ef; dw9-17 = er; dw18-26 = ei; dw27 pad
__global__ __launch_bounds__(256) void edge_kernel(
    const int* __restrict__ recv, const int* __restrict__ senders,
    const int* __restrict__ species, const int* __restrict__ offsets,
    int* __restrict__ cursor, const int* __restrict__ counts,
    const int* __restrict__ dstart, int* __restrict__ degcur,
    int* __restrict__ perm, const float* __restrict__ ef,
    const float* __restrict__ ear, const float* __restrict__ eai,
    float* __restrict__ blk) {
  int e = blockIdx.x * 256 + threadIdx.x;
  if (e < NN) {  // node perm scatter (balanced: descending degree)
    int d = min(counts[e], 63);
    int pos = atomicAdd(&degcur[d], 1);
    perm[dstart[d] + pos] = e;
  }
  if (e >= EE) return;
  int r = recv[e];
  int pos = atomicAdd(&cursor[r], 1);
  int slot = offsets[r] + pos;
  int s = senders[e];
  int a = species[s];
  const float* efp = ef + (size_t)e * 8;
  const float* erp = ear + (size_t)e * 9;
  const float* eip = eai + (size_t)e * 9;
  float4* dst = (float4*)(blk + (size_t)slot * 28);
  float4 q;
  q.x = __int_as_float(s | (a << 20)); q.y = efp[0]; q.z = efp[1]; q.w = efp[2];
  dst[0] = q;
  q.x = efp[3]; q.y = efp[4]; q.z = efp[5]; q.w = efp[6];
  dst[1] = q;
  q.x = efp[7]; q.y = erp[0]; q.z = erp[1]; q.w = erp[2];
  dst[2] = q;
  q.x = erp[3]; q.y = erp[4]; q.z = erp[5]; q.w = erp[6];
  dst[3] = q;
  q.x = erp[7]; q.y = erp[8]; q.z = eip[0]; q.w = eip[1];
  dst[4] = q;
  q.x = eip[2]; q.y = eip[3]; q.z = eip[4]; q.w = eip[5];
  dst[5] = q;
  q.x = eip[6]; q.y = eip[7]; q.z = eip[8]; q.w = 0.f;
  dst[6] = q;
}

#define RLF(V, L) __int_as_float(__builtin_amdgcn_readlane((V), (L)))

// one edge: payload in SGPR arrays, weights per-lane LDS b128, acc in VGPRs
#define EDGE2(EFA, ERA, EIA, PKV, XS) do {                                 \
  int a_ = (PKV) >> 20;                                                    \
  const float4* wp_ = (const float4*)(lds + a_ * 1792 + lane * 28);        \
  float4 w_[6];                                                            \
  _Pragma("unroll") for (int g_ = 0; g_ < 6; ++g_) w_[g_] = wp_[gpi[g_]];  \
  float t0_ = 0.f, t1_ = 0.f, t2_ = 0.f;                                   \
  _Pragma("unroll") for (int r_ = 0; r_ < 8; ++r_) {                       \
    t0_ = fmaf((EFA)[r_], comp4(w_[(r_ * 3 + 0) >> 2], (r_ * 3 + 0) & 3), t0_); \
    t1_ = fmaf((EFA)[r_], comp4(w_[(r_ * 3 + 1) >> 2], (r_ * 3 + 1) & 3), t1_); \
    t2_ = fmaf((EFA)[r_], comp4(w_[(r_ * 3 + 2) >> 2], (r_ * 3 + 2) & 3), t2_); \
  }                                                                        \
  t0_ *= (XS); t1_ *= (XS); t2_ *= (XS);                                   \
  accR[0] = fmaf(t0_, (ERA)[0], accR[0]);                                  \
  accI[0] = fmaf(t0_, (EIA)[0], accI[0]);                                  \
  _Pragma("unroll") for (int m_ = 1; m_ < 4; ++m_) {                       \
    accR[m_] = fmaf(t1_, (ERA)[m_], accR[m_]);                             \
    accI[m_] = fmaf(t1_, (EIA)[m_], accI[m_]);                             \
  }                                                                        \
  _Pragma("unroll") for (int m_ = 4; m_ < 9; ++m_) {                       \
    accR[m_] = fmaf(t2_, (ERA)[m_], accR[m_]);                             \
    accI[m_] = fmaf(t2_, (EIA)[m_], accI[m_]);                             \
  }                                                                        \
} while (0)

// mix: out[v][m] = sum_u acc[u][m] * W[u][v]; W per-lane from swizzled LDS
#define MIXL(LV, M0, M1)                                                    \
  _Pragma("unroll") for (int q_ = 0; q_ < 16; ++q_) {                       \
    float4 w4_ = *(const float4*)&lds[(LV) * 4096 + lane * 64 +             \
                                      ((q_ + lane) & 15) * 4];              \
    _Pragma("unroll") for (int j_ = 0; j_ < 4; ++j_) {                      \
      float wu_ = comp4(w4_, j_);                                           \
      _Pragma("unroll") for (int m_ = (M0); m_ < (M1); ++m_) {              \
        outR[m_] = fmaf(RLF(__float_as_int(accR[m_]), q_ * 4 + j_), wu_, outR[m_]); \
        outI[m_] = fmaf(RLF(__float_as_int(accI[m_]), q_ * 4 + j_), wu_, outI[m_]); \
      }                                                                     \
    }                                                                       \
  }

// FUSED gather + per-l linear. One node per wave (degree-sorted via perm),
// 8 waves/block, 2 blocks/CU by LDS.
__global__ __launch_bounds__(512, 4) void fused_kernel(
    const float* __restrict__ h, const int* __restrict__ offs,
    const float* __restrict__ blkd, const int* __restrict__ perm,
    const float* __restrict__ W_tpw, const float* __restrict__ wlt,
    float* __restrict__ out) {
  __shared__ float lds[17920];  // 71680 B
  // stage W_tpw -> [a][u][28], group g at slot gp=(g+5u)%7
  for (int t = threadIdx.x; t < AA * 6 * 64; t += 512) {
    int a = t / 384, rem = t - a * 384;
    int g = rem >> 6, u = rem & 63;
    int gp = (g + 5 * u) % 7;
    const float* src = W_tpw + a * 1536 + g * 256 + u;  // k-major, stride 64
    float4 w;
    w.x = src[0]; w.y = src[64]; w.z = src[128]; w.w = src[192];
    *(float4*)&lds[a * 1792 + u * 28 + gp * 4] = w;
  }
  __syncthreads();
  int wid = __builtin_amdgcn_readfirstlane(threadIdx.x >> 6);
  int lane = threadIdx.x & 63;
  int n = __builtin_amdgcn_readfirstlane(perm[blockIdx.x * 8 + wid]);
  int gpi[6];
#pragma unroll
  for (int g = 0; g < 6; ++g) gpi[g] = (g + 5 * lane) % 7;
  float accR[9], accI[9];
#pragma unroll
  for (int m = 0; m < 9; ++m) { accR[m] = 0.f; accI[m] = 0.f; }
  int beg = __builtin_amdgcn_readfirstlane(offs[n]);
  int end_ = __builtin_amdgcn_readfirstlane(offs[n + 1]);
  if (end_ > beg) {
    const int* bi = (const int*)blkd;
    int pk0 = bi[(size_t)beg * 28];           // uniform -> s_load
    int pk1 = (beg + 1 < end_) ? bi[(size_t)(beg + 1) * 28] : pk0;
    float xs0 = h[(size_t)(pk0 & 0xFFFFF) * 64 + lane];  // coalesced
    float xs1 = h[(size_t)(pk1 & 0xFFFFF) * 64 + lane];
    float efc[8], erc[9], eic[9];
    {
      const float* ep = blkd + (size_t)beg * 28;  // uniform -> s_load
#pragma unroll
      for (int i = 0; i < 8; ++i) efc[i] = ep[1 + i];
#pragma unroll
      for (int i = 0; i < 9; ++i) erc[i] = ep[9 + i];
#pragma unroll
      for (int i = 0; i < 9; ++i) eic[i] = ep[18 + i];
    }
    for (int idx = beg; idx < end_; ++idx) {
      // prefetch idx+2 pk/h (2-deep covers blk->h chain)
      int pk2 = pk0;
      float xs2 = 0.f;
      if (idx + 2 < end_) {
        pk2 = bi[(size_t)(idx + 2) * 28];
        xs2 = h[(size_t)(pk2 & 0xFFFFF) * 64 + lane];
      }
      // prefetch idx+1 payload (1-deep, SMEM latency under compute)
      float efn[8], ern[9], ein[9];
      if (idx + 1 < end_) {
        const float* ep = blkd + (size_t)(idx + 1) * 28;
#pragma unroll
        for (int i = 0; i < 8; ++i) efn[i] = ep[1 + i];
#pragma unroll
        for (int i = 0; i < 9; ++i) ern[i] = ep[9 + i];
#pragma unroll
        for (int i = 0; i < 9; ++i) ein[i] = ep[18 + i];
      } else {
#pragma unroll
        for (int i = 0; i < 8; ++i) efn[i] = 0.f;
#pragma unroll
        for (int i = 0; i < 9; ++i) { ern[i] = 0.f; ein[i] = 0.f; }
      }
      EDGE2(efc, erc, eic, pk0, xs0);
      pk0 = pk1; xs0 = xs1;
      pk1 = pk2; xs1 = xs2;
#pragma unroll
      for (int i = 0; i < 8; ++i) efc[i] = efn[i];
#pragma unroll
      for (int i = 0; i < 9; ++i) { erc[i] = ern[i]; eic[i] = ein[i]; }
    }
  }
  __builtin_amdgcn_sched_barrier(0);
  __syncthreads();  // all waves done with W_tpw region (degree-balanced)
  // stage wlt -> lds[l][v][64], group q at slot (q+v)&15
  for (int t = threadIdx.x; t < 3072; t += 512) {
    int l = t >> 10, rem = t & 1023, v = rem >> 4, q = rem & 15;
    int slot = (q + v) & 15;
    float4 w = *(const float4*)(wlt + l * 4096 + v * 64 + q * 4);
    *(float4*)&lds[l * 4096 + v * 64 + slot * 4] = w;
  }
  __syncthreads();
  float outR[9], outI[9];
#pragma unroll
  for (int m = 0; m < 9; ++m) { outR[m] = 0.f; outI[m] = 0.f; }
  MIXL(0, 0, 1)
  MIXL(1, 1, 4)
  MIXL(2, 4, 9)
  // staged coalesced output; stg region (12288..16896) disjoint from wlt
  const float SCL = 0.0078125f;  // (1/sqrt(64))/16
  float* stg = lds + 12288 + wid * 576;
#pragma unroll
  for (int m = 0; m < 9; ++m) stg[lane * 9 + m] = outR[m] * SCL;
  __builtin_amdgcn_s_waitcnt(0);
#pragma unroll
  for (int k = 0; k < 9; ++k)
    out[(size_t)n * 576 + k * 64 + lane] = stg[k * 64 + lane];
#pragma unroll
  for (int m = 0; m < 9; ++m) stg[lane * 9 + m] = outI[m] * SCL;
  __builtin_amdgcn_s_waitcnt(0);
#pragma unroll
  for (int k = 0; k < 9; ++k)
    out[NC9 + (size_t)n * 576 + k * 64 + lane] = stg[k * 64 + lane];
}

extern "C" void kernel_launch(void* const* d_in, const int* in_sizes, int n_in,
                              void* d_out, int out_size, void* d_ws, size_t ws_size,
                              hipStream_t stream) {
  const float* node_attrs = (const float*)d_in[0];
  const float* node_feats = (const float*)d_in[1];
  const float* ear        = (const float*)d_in[2];
  const float* eai        = (const float*)d_in[3];
  const float* ef         = (const float*)d_in[4];
  const int*   senders    = (const int*)d_in[5];
  const int*   receivers  = (const int*)d_in[6];
  const float* W_up       = (const float*)d_in[7];
  const float* W_tpw      = (const float*)d_in[8];
  const float* W_lin      = (const float*)d_in[9];
  const float* W_skip     = (const float*)d_in[10];
  float* out = (float*)d_out;

  char* ws = (char*)d_ws;
  float* h        = (float*)(ws + WS_H);
  float* blk      = (float*)(ws + WS_BLK);
  float* wlt      = (float*)(ws + WS_WLT);
  int*   species  = (int*)(ws + WS_SPECIES);
  int*   counts   = (int*)(ws + WS_COUNTS);
  int*   cursor   = (int*)(ws + WS_CURSOR);
  int*   offsets  = (int*)(ws + WS_OFFSETS);
  int*   perm     = (int*)(ws + WS_PERM);
  int*   dstart   = (int*)(ws + WS_DSTART);
  int*   degcur   = (int*)(ws + WS_DEGCUR);

  // zero counts + cursor (contiguous 128 KB); degcur zeroed in scan_kernel
  hipMemsetAsync(ws + WS_COUNTS, 0, 128000, stream);

  prep_kernel<<<1000, 256, 0, stream>>>(node_attrs, receivers, W_lin,
                                        node_feats, W_up, W_skip,
                                        species, counts, wlt, h, out);
  scan_kernel<<<1, 1024, 0, stream>>>(counts, offsets, dstart, degcur);
  edge_kernel<<<1000, 256, 0, stream>>>(receivers, senders, species, offsets,
                                        cursor, counts, dstart, degcur, perm,
                                        ef, ear, eai, blk);
  fused_kernel<<<2000, 512, 0, stream>>>(h, offsets, blk, perm, W_tpw, wlt,
                                         out);
}

// Round 9
// 339.243 us; speedup vs baseline: 1.0366x; 1.0366x over previous
//
#include <hip/hip_runtime.h>
#include <hip/hip_bf16.h>

#define NN 16000
#define EE 256000
#define CC 64
#define AA 10
#define RR 8
#define NC9 9216000      // N*C*9
#define SC_OFF 18432000  // 2*N*C*9

// ---------------- workspace layout (bytes) ----------------
#define WS_H        0           // [N][64] f32
#define WS_EP2      4096000     // [E] int2 (e, s|a<<20), CSR-slot order
#define WS_WLT      6144000     // [3][64][64] f32 (W_lin transposed)
#define WS_SPECIES  6193152
#define WS_COUNTS   6257152
#define WS_CURSOR   6321152
#define WS_OFFSETS  6385152     // [N+1]
#define WS_PERM     6449216     // [N] degree-sorted node ids
#define WS_DSTART   6513216     // [64]
#define WS_DEGCUR   6513472     // [64]

__device__ __forceinline__ float comp4(float4 v, int j) {
  return j == 0 ? v.x : j == 1 ? v.y : j == 2 ? v.z : v.w;
}
// force value into SGPR (load address is uniform; insurance for regalloc)
__device__ __forceinline__ float rflf(float v) {
  return __int_as_float(__builtin_amdgcn_readfirstlane(__float_as_int(v)));
}

// species + W_lin transpose + receiver histogram
__global__ __launch_bounds__(256) void prep_kernel(
    const float* __restrict__ attrs, const int* __restrict__ recv,
    const float* __restrict__ W_lin, int* __restrict__ species,
    int* __restrict__ counts, float* __restrict__ wlt) {
  int i = blockIdx.x * 256 + threadIdx.x;
  if (i < NN) {
    const float* p = attrs + (size_t)i * AA;
    int sp = 0;
#pragma unroll
    for (int a = 1; a < AA; ++a)
      if (p[a] > 0.5f) sp = a;
    species[i] = sp;
  }
  if (i < 3 * 64 * 64) {  // wlt[l][v][u] = W_lin[l][u][v]
    int l = i >> 12, rem = i & 4095, v = rem >> 6, u = rem & 63;
    wlt[i] = W_lin[l * 4096 + u * 64 + v];
  }
  if (i < EE) atomicAdd(&counts[recv[i]], 1);
}

// h = (nf @ W_up)/8 ; sc = (nf . W_skip[:,a,:])/sqrt(640). W_up in LDS.
__global__ __launch_bounds__(256) void node_kernel(
    const float* __restrict__ nf, const float* __restrict__ attrs,
    const float* __restrict__ W_up, const float* __restrict__ W_skip,
    float* __restrict__ h, float* __restrict__ out) {
  __shared__ float sW[4096];
  for (int t = threadIdx.x; t < 4096; t += 256) sW[t] = W_up[t];
  __syncthreads();
  int wid = __builtin_amdgcn_readfirstlane(threadIdx.x >> 6);
  int lane = threadIdx.x & 63;
  int n = blockIdx.x * 4 + wid;
  if (n >= NN) return;
  const float* ap = attrs + (size_t)n * AA;  // uniform -> s_load
  int a = 0;
#pragma unroll
  for (int j = 1; j < AA; ++j)
    if (ap[j] > 0.5f) a = j;
  const float* nfp = nf + (size_t)n * 64;
  const float* wsk = W_skip + (size_t)a * 64;
  float hacc = 0.f, sacc = 0.f;
#pragma unroll
  for (int u = 0; u < 64; ++u) {
    float x = nfp[u];  // uniform -> s_load
    hacc = fmaf(x, sW[u * 64 + lane], hacc);
    sacc = fmaf(x, wsk[u * 640 + lane], sacc);
  }
  h[(size_t)n * 64 + lane] = hacc * 0.125f;
  out[SC_OFF + (size_t)n * 64 + lane] = sacc * 0.03952847075210474f;
}

// single block: exclusive scan counts->offsets + descending degree buckets
__global__ __launch_bounds__(1024) void scan_kernel(
    const int* __restrict__ counts, int* __restrict__ offsets,
    int* __restrict__ dstart, int* __restrict__ degcur) {
  __shared__ int part[1024];
  __shared__ int hist[64];
  int tid = threadIdx.x;
  if (tid < 64) { hist[tid] = 0; degcur[tid] = 0; }
  __syncthreads();
  const int CH = 16;
  int base = tid * CH;
  int loc[CH];
  int s = 0;
#pragma unroll
  for (int i = 0; i < CH; ++i) {
    int idx = base + i;
    int c = (idx < NN) ? counts[idx] : 0;
    loc[i] = c;
    s += c;
  }
  part[tid] = s;
  __syncthreads();
  for (int off = 1; off < 1024; off <<= 1) {
    int t = part[tid];
    int add = (tid >= off) ? part[tid - off] : 0;
    __syncthreads();
    part[tid] = t + add;
    __syncthreads();
  }
  int pre = (tid > 0) ? part[tid - 1] : 0;
#pragma unroll
  for (int i = 0; i < CH; ++i) {
    int idx = base + i;
    if (idx <= NN) offsets[idx] = pre;
    pre += loc[i];
    if (idx < NN) atomicAdd(&hist[min(loc[i], 63)], 1);
  }
  __syncthreads();
  if (tid == 0) {
    int run = 0;
    for (int d = 63; d >= 0; --d) { dstart[d] = run; run += hist[d]; }
  }
}

// CSR slot fill (8-B records) + degree-sorted node perm
__global__ __launch_bounds__(256) void edge_kernel(
    const int* __restrict__ recv, const int* __restrict__ senders,
    const int* __restrict__ species, const int* __restrict__ offsets,
    int* __restrict__ cursor, const int* __restrict__ counts,
    const int* __restrict__ dstart, int* __restrict__ degcur,
    int* __restrict__ perm, int2* __restrict__ ep2) {
  int e = blockIdx.x * 256 + threadIdx.x;
  if (e < NN) {  // node perm scatter (descending degree)
    int d = min(counts[e], 63);
    int pos = atomicAdd(&degcur[d], 1);
    perm[dstart[d] + pos] = e;
  }
  if (e >= EE) return;
  int r = recv[e];
  int pos = atomicAdd(&cursor[r], 1);
  int slot = offsets[r] + pos;
  int s = senders[e];
  int a = species[s];
  ep2[slot] = make_int2(e, s | (a << 20));
}

// one edge: payload via uniform s_loads, weights per-lane LDS b128
#define EDGE3(RC, XS) do {                                                 \
  int e_ = (RC).x;                                                         \
  int a_ = (RC).y >> 20;                                                   \
  const float* efp_ = ef + (size_t)e_ * 8;   /* uniform -> s_load */       \
  const float* erp_ = ear + (size_t)e_ * 9;                                \
  const float* eip_ = eai + (size_t)e_ * 9;                                \
  float efs_[8], ers_[9], eis_[9];                                         \
  _Pragma("unroll") for (int i_ = 0; i_ < 8; ++i_) efs_[i_] = rflf(efp_[i_]); \
  _Pragma("unroll") for (int i_ = 0; i_ < 9; ++i_) ers_[i_] = rflf(erp_[i_]); \
  _Pragma("unroll") for (int i_ = 0; i_ < 9; ++i_) eis_[i_] = rflf(eip_[i_]); \
  const float4* wp_ = (const float4*)(lds + a_ * 1792 + lane * 28);        \
  float4 w_[6];                                                            \
  _Pragma("unroll") for (int g_ = 0; g_ < 6; ++g_) w_[g_] = wp_[g_];       \
  float t0_ = 0.f, t1_ = 0.f, t2_ = 0.f;                                   \
  _Pragma("unroll") for (int r_ = 0; r_ < 8; ++r_) {                       \
    t0_ = fmaf(efs_[r_], comp4(w_[(r_ * 3 + 0) >> 2], (r_ * 3 + 0) & 3), t0_); \
    t1_ = fmaf(efs_[r_], comp4(w_[(r_ * 3 + 1) >> 2], (r_ * 3 + 1) & 3), t1_); \
    t2_ = fmaf(efs_[r_], comp4(w_[(r_ * 3 + 2) >> 2], (r_ * 3 + 2) & 3), t2_); \
  }                                                                        \
  t0_ *= (XS); t1_ *= (XS); t2_ *= (XS);                                   \
  accR[0] = fmaf(t0_, ers_[0], accR[0]);                                   \
  accI[0] = fmaf(t0_, eis_[0], accI[0]);                                   \
  _Pragma("unroll") for (int m_ = 1; m_ < 4; ++m_) {                       \
    accR[m_] = fmaf(t1_, ers_[m_], accR[m_]);                              \
    accI[m_] = fmaf(t1_, eis_[m_], accI[m_]);                              \
  }                                                                        \
  _Pragma("unroll") for (int m_ = 4; m_ < 9; ++m_) {                       \
    accR[m_] = fmaf(t2_, ers_[m_], accR[m_]);                              \
    accI[m_] = fmaf(t2_, eis_[m_], accI[m_]);                              \
  }                                                                        \
} while (0)

#define RLF(V, L) __int_as_float(__builtin_amdgcn_readlane((V), (L)))

// mix: out[v][m] = sum_u acc[u][m] * W[u][v]; W per-lane from swizzled LDS
#define MIXL(LV, M0, M1)                                                    \
  _Pragma("unroll") for (int q_ = 0; q_ < 16; ++q_) {                       \
    float4 w4_ = *(const float4*)&lds[(LV) * 4096 + lane * 64 +             \
                                      ((q_ + lane) & 15) * 4];              \
    _Pragma("unroll") for (int j_ = 0; j_ < 4; ++j_) {                      \
      float wu_ = comp4(w4_, j_);                                           \
      _Pragma("unroll") for (int m_ = (M0); m_ < (M1); ++m_) {              \
        outR[m_] = fmaf(RLF(__float_as_int(accR[m_]), q_ * 4 + j_), wu_, outR[m_]); \
        outI[m_] = fmaf(RLF(__float_as_int(accI[m_]), q_ * 4 + j_), wu_, outI[m_]); \
      }                                                                     \
    }                                                                       \
  }

// FUSED gather + per-l linear. One node per wave (degree-sorted via perm),
// 8 waves/block, 2 blocks/CU by LDS (71680 B).
// LDS W_tpw layout [a][u][28]: row 112 B = 7 bank-quads; b128 read at
// lane*28+g*4 dwords -> quad (7*lane+g)%8, a permutation (7 coprime 8):
// conflict-free on BOTH the staged write and the per-edge read. No rotation.
__global__ __launch_bounds__(512, 4) void fused_kernel(
    const float* __restrict__ h, const int* __restrict__ offs,
    const int2* __restrict__ ep2, const int* __restrict__ perm,
    const float* __restrict__ ef, const float* __restrict__ ear,
    const float* __restrict__ eai, const float* __restrict__ W_tpw,
    const float* __restrict__ wlt, float* __restrict__ out) {
  __shared__ float lds[17920];  // 71680 B
  for (int t = threadIdx.x; t < AA * 6 * 64; t += 512) {
    int a = t / 384, rem = t - a * 384;
    int g = rem >> 6, u = rem & 63;
    const float* src = W_tpw + a * 1536 + g * 256 + u;  // k-major, stride 64
    float4 w;
    w.x = src[0]; w.y = src[64]; w.z = src[128]; w.w = src[192];
    *(float4*)&lds[a * 1792 + u * 28 + g * 4] = w;
  }
  __syncthreads();
  int wid = __builtin_amdgcn_readfirstlane(threadIdx.x >> 6);
  int lane = threadIdx.x & 63;
  int n = __builtin_amdgcn_readfirstlane(perm[blockIdx.x * 8 + wid]);
  float accR[9], accI[9];
#pragma unroll
  for (int m = 0; m < 9; ++m) { accR[m] = 0.f; accI[m] = 0.f; }
  int beg = __builtin_amdgcn_readfirstlane(offs[n]);
  int end_ = __builtin_amdgcn_readfirstlane(offs[n + 1]);
  if (end_ > beg) {
    int2 r0 = ep2[beg];  // uniform -> s_load_dwordx2
    int2 r1 = (beg + 1 < end_) ? ep2[beg + 1] : r0;
    float xs0 = h[(size_t)(r0.y & 0xFFFFF) * 64 + lane];  // coalesced
    float xs1 = h[(size_t)(r1.y & 0xFFFFF) * 64 + lane];
    for (int idx = beg; idx < end_; ++idx) {
      int2 r2 = r0;
      float xs2 = 0.f;
      if (idx + 2 < end_) {  // depth-2 prefetch covers rec->h chain
        r2 = ep2[idx + 2];
        xs2 = h[(size_t)(r2.y & 0xFFFFF) * 64 + lane];
      }
      EDGE3(r0, xs0);
      r0 = r1; xs0 = xs1;
      r1 = r2; xs1 = xs2;
    }
  }
  __builtin_amdgcn_sched_barrier(0);
  __syncthreads();  // all waves done with W_tpw region (degree-balanced)
  // stage wlt -> lds[l][v][64], group q at slot (q+v)&15
  for (int t = threadIdx.x; t < 3072; t += 512) {
    int l = t >> 10, rem = t & 1023, v = rem >> 4, q = rem & 15;
    int slot = (q + v) & 15;
    float4 w = *(const float4*)(wlt + l * 4096 + v * 64 + q * 4);
    *(float4*)&lds[l * 4096 + v * 64 + slot * 4] = w;
  }
  __syncthreads();
  float outR[9], outI[9];
#pragma unroll
  for (int m = 0; m < 9; ++m) { outR[m] = 0.f; outI[m] = 0.f; }
  MIXL(0, 0, 1)
  MIXL(1, 1, 4)
  MIXL(2, 4, 9)
  // staged coalesced output; stg region (12288..16896) disjoint from wlt
  const float SCL = 0.0078125f;  // (1/sqrt(64))/16
  float* stg = lds + 12288 + wid * 576;
#pragma unroll
  for (int m = 0; m < 9; ++m) stg[lane * 9 + m] = outR[m] * SCL;
  __builtin_amdgcn_s_waitcnt(0);
#pragma unroll
  for (int k = 0; k < 9; ++k)
    out[(size_t)n * 576 + k * 64 + lane] = stg[k * 64 + lane];
#pragma unroll
  for (int m = 0; m < 9; ++m) stg[lane * 9 + m] = outI[m] * SCL;
  __builtin_amdgcn_s_waitcnt(0);
#pragma unroll
  for (int k = 0; k < 9; ++k)
    out[NC9 + (size_t)n * 576 + k * 64 + lane] = stg[k * 64 + lane];
}

extern "C" void kernel_launch(void* const* d_in, const int* in_sizes, int n_in,
                              void* d_out, int out_size, void* d_ws, size_t ws_size,
                              hipStream_t stream) {
  const float* node_attrs = (const float*)d_in[0];
  const float* node_feats = (const float*)d_in[1];
  const float* ear        = (const float*)d_in[2];
  const float* eai        = (const float*)d_in[3];
  const float* ef         = (const float*)d_in[4];
  const int*   senders    = (const int*)d_in[5];
  const int*   receivers  = (const int*)d_in[6];
  const float* W_up       = (const float*)d_in[7];
  const float* W_tpw      = (const float*)d_in[8];
  const float* W_lin      = (const float*)d_in[9];
  const float* W_skip     = (const float*)d_in[10];
  float* out = (float*)d_out;

  char* ws = (char*)d_ws;
  float* h        = (float*)(ws + WS_H);
  int2*  ep2      = (int2*)(ws + WS_EP2);
  float* wlt      = (float*)(ws + WS_WLT);
  int*   species  = (int*)(ws + WS_SPECIES);
  int*   counts   = (int*)(ws + WS_COUNTS);
  int*   cursor   = (int*)(ws + WS_CURSOR);
  int*   offsets  = (int*)(ws + WS_OFFSETS);
  int*   perm     = (int*)(ws + WS_PERM);
  int*   dstart   = (int*)(ws + WS_DSTART);
  int*   degcur   = (int*)(ws + WS_DEGCUR);

  // zero counts + cursor (contiguous 128 KB); degcur zeroed in scan_kernel
  hipMemsetAsync(ws + WS_COUNTS, 0, 128000, stream);

  prep_kernel<<<1000, 256, 0, stream>>>(node_attrs, receivers, W_lin,
                                        species, counts, wlt);
  node_kernel<<<4000, 256, 0, stream>>>(node_feats, node_attrs, W_up, W_skip,
                                        h, out);
  scan_kernel<<<1, 1024, 0, stream>>>(counts, offsets, dstart, degcur);
  edge_kernel<<<1000, 256, 0, stream>>>(receivers, senders, species, offsets,
                                        cursor, counts, dstart, degcur, perm,
                                        ep2);
  fused_kernel<<<2000, 512, 0, stream>>>(h, offsets, ep2, perm, ef, ear, eai,
                                         W_tpw, wlt, out);
}